// Round 1
// baseline (43.509 us; speedup 1.0000x reference)
//
#include <hip/hip_runtime.h>

// out[b,i,w] = sum_{ch=0..30} x[b,i,w,ch] * sign(w)[((i-ch)&31)*32 + (w&31)]
// (the forward/backward rolls cancel on x; the mask gets rolled instead,
//  and the 2x2-tiled 64x64 mask reduces mod 32)

#define B_ 512
#define H_ 64
#define W_ 64
#define CH_ 31
#define ROWS_PER_BLOCK 4
#define ROW_FLOATS (W_ * CH_)                      // 1984 floats = 7936 B per (b,i) row
#define TILE_FLOATS (ROWS_PER_BLOCK * ROW_FLOATS)  // 7936 floats
#define TILE_F4 (TILE_FLOATS / 4)                  // 1984 float4

__global__ __launch_bounds__(256)
void codednet_kernel(const float* __restrict__ x,
                     const float* __restrict__ wts,
                     float* __restrict__ out) {
    __shared__ float sx[TILE_FLOATS];
    __shared__ unsigned smask[32];

    const int tid = threadIdx.x;
    const long long rowBase = (long long)blockIdx.x * ROWS_PER_BLOCK;

    // --- pack sign bits of the 32x32 mask, one column per thread (4 KB, L1-hot)
    if (tid < 32) {
        unsigned bits = 0;
        #pragma unroll
        for (int r = 0; r < 32; ++r)
            bits |= ((__float_as_uint(wts[r * 32 + tid]) >> 31) & 1u) << r;
        smask[tid] = bits;
    }

    // --- stage 4 rows of x into LDS, fully coalesced float4
    const float4* __restrict__ src4 =
        (const float4*)(x + rowBase * ROW_FLOATS);  // rowBase*7936B is 16B-aligned
    float4* dst4 = (float4*)sx;
    for (int j = tid; j < TILE_F4; j += 256) dst4[j] = src4[j];

    __syncthreads();

    // --- compute: one thread per output element
    const int r = tid >> 6;          // row within tile (one wave per row)
    const int w = tid & 63;          // W coordinate = lane
    const long long row = rowBase + r;
    const int i = (int)(row & 63);   // H coordinate

    // rotate so the per-ch bit index becomes a compile-time constant:
    // bit ((i-ch)&31) of bits == bit ((-ch)&31) of rotr(bits, i&31)
    const unsigned rb = __builtin_rotateright32(smask[w & 31], (unsigned)(i & 31));

    const float* __restrict__ xr = sx + r * ROW_FLOATS + w * CH_;
    float acc = 0.0f;
    #pragma unroll
    for (int ch = 0; ch < CH_; ++ch) {
        // select bit (32-ch)&31 -> move to the sign position
        const unsigned s = (rb << ((ch - 1) & 31)) & 0x80000000u;
        acc += __uint_as_float(__float_as_uint(xr[ch]) ^ s);
    }

    out[row * 64 + w] = acc;
}

extern "C" void kernel_launch(void* const* d_in, const int* in_sizes, int n_in,
                              void* d_out, int out_size, void* d_ws, size_t ws_size,
                              hipStream_t stream) {
    const float* x = (const float*)d_in[0];
    const float* w = (const float*)d_in[1];
    float* out = (float*)d_out;

    const int n_rows = B_ * H_;                    // 32768
    const int grid = n_rows / ROWS_PER_BLOCK;      // 8192
    codednet_kernel<<<grid, 256, 0, stream>>>(x, w, out);
}